// Round 17
// baseline (185.281 us; speedup 1.0000x reference)
//
#include <hip/hip_runtime.h>

// Problem constants
#define B_  4
#define S_  2048
#define D_  1024
#define H_  16
#define HD_ 64
#define M_  (B_*S_)   // 8192 rows total

typedef _Float16 f16;
typedef f16  f16x8 __attribute__((ext_vector_type(8)));
typedef f16  f16x4 __attribute__((ext_vector_type(4)));
typedef float f32x4 __attribute__((ext_vector_type(4)));

// global -> LDS direct DMA, 16B per lane. LDS dest = wave-uniform base + lane*16.
__device__ __forceinline__ void gload_lds16(const f16* g, f16* l) {
    __builtin_amdgcn_global_load_lds(
        (const __attribute__((address_space(1))) void*)g,
        (__attribute__((address_space(3))) void*)l, 16, 0, 0);
}

// ---------------------------------------------------------------- converts (fused, grid-stride)
__global__ __launch_bounds__(256) void cvt2_kernel(const float* __restrict__ a,
                                                   const float* __restrict__ c,
                                                   f16* __restrict__ out, int n4each) {
    const int n4tot = 2 * n4each;
    for (int i = blockIdx.x * 256 + threadIdx.x; i < n4tot; i += gridDim.x * 256) {
        const float* src = (i < n4each) ? a : c;
        int j = (i < n4each) ? i : i - n4each;
        f32x4 v = *reinterpret_cast<const f32x4*>(src + (size_t)j * 4);
        *reinterpret_cast<f16x4*>(out + (size_t)i * 4) = __builtin_convertvector(v, f16x4);
    }
}

// all four weights W[K][N] f32 -> WT[N][K] f16 (outputs contiguous per z)
__global__ __launch_bounds__(256) void transpose_cvt4_kernel(const float* __restrict__ Wq,
                                                             const float* __restrict__ Wk,
                                                             const float* __restrict__ Wv,
                                                             const float* __restrict__ Wo,
                                                             f16* __restrict__ WT) {
    __shared__ float tile[32][33];
    const int z = blockIdx.z;
    const float* W = (z == 0) ? Wq : (z == 1) ? Wk : (z == 2) ? Wv : Wo;
    f16* dst = WT + (size_t)z * D_ * D_;
    const int n0 = blockIdx.x * 32, k0 = blockIdx.y * 32;
    const int tx = threadIdx.x & 31, ty = threadIdx.x >> 5; // (32,8)
#pragma unroll
    for (int j = 0; j < 4; ++j)
        tile[ty + 8 * j][tx] = W[(size_t)(k0 + ty + 8 * j) * D_ + n0 + tx];
    __syncthreads();
#pragma unroll
    for (int j = 0; j < 4; ++j)
        dst[(size_t)(n0 + ty + 8 * j) * D_ + k0 + tx] = (f16)tile[tx][ty + 8 * j];
}

// ---------------------------------------------------------------- triple-buffered GEMM, BM=128 x BN=256, BK=32
// 256 threads = 4 waves (2M x 2N); per-wave 64x128 out (4m x 8n). LDS 72KB = 3 bufs.
// Depth-2 staging, counted vmcnt(6) (never drains mid-loop).
// MODE 0: one QKV segment per DISPATCH (seg arg: 0=Q,1=K,2=V) — 256 blocks each;
//   dispatch boundary enforces temporal L2 isolation (per-XCD set = 2MB B + 2MB A).
//   (768-block fused version co-ran 2 segments -> 8MB/XCD -> L2 thrash.)
// MODE 1: output GEMM f32, 256 blocks.
template <int MODE>
__global__ __launch_bounds__(256, 2) void gemm3p(const f16* __restrict__ Adata,
                                                 const f16* __restrict__ Actx,
                                                 const f16* __restrict__ Wbase,
                                                 const float* __restrict__ b0,
                                                 const float* __restrict__ b1,
                                                 const float* __restrict__ b2,
                                                 f16* __restrict__ Qb,
                                                 f16* __restrict__ Kb,
                                                 f16* __restrict__ VtB,
                                                 float* __restrict__ Cout,
                                                 int seg) {
    extern __shared__ __align__(16) f16 SM[]; // 3 x 12288 f16 (A 4096 + B 8192 each)
    constexpr int K = D_;
    constexpr int NT = K / 32;
    const int sid = (int)blockIdx.x;                   // 0..255
    const int work = (sid & 7) * 32 + (sid >> 3);      // XCD-chunked, bijective
    const int wy = work >> 2, wx = work & 3;           // 64 x 4
    const f16* __restrict__ A = (MODE == 0) ? (seg ? Actx : Adata) : Adata;
    const f16* __restrict__ Wt = Wbase + (size_t)seg * D_ * D_;
    const int m0 = wy * 128, n0 = wx * 256;
    const int tid = (int)threadIdx.x;
    const int w = tid >> 6, lr = tid & 15, lg = (tid & 63) >> 4;
    const int wr = w >> 1, wc = w & 1;
    const int sw = (lr >> 1) & 3;

    auto stage = [&](int buf, int kt) {
        const int kk0 = kt * 32;
        f16* base = SM + buf * 12288;
#pragma unroll
        for (int j = 0; j < 2; ++j) {
            const int c = j * 256 + tid;
            const int row = c >> 2;
            const int ks = ((c & 3) ^ ((row >> 1) & 3)) * 8; // pre-swizzled k-slot
            gload_lds16(A + (size_t)(m0 + row) * K + kk0 + ks,
                        base + (j * 256 + w * 64) * 8);
        }
#pragma unroll
        for (int j = 0; j < 4; ++j) {
            const int c = j * 256 + tid;
            const int row = c >> 2;
            const int ks = ((c & 3) ^ ((row >> 1) & 3)) * 8;
            gload_lds16(Wt + (size_t)(n0 + row) * K + kk0 + ks,
                        base + 4096 + (j * 256 + w * 64) * 8);
        }
    };
    auto LDA = [&](int buf, int m) -> f16x8 {
        return *reinterpret_cast<const f16x8*>(
            SM + buf * 12288 + (wr * 64 + m * 16 + lr) * 32 + ((lg ^ sw) * 8));
    };
    auto LDB = [&](int buf, int n) -> f16x8 {
        return *reinterpret_cast<const f16x8*>(
            SM + buf * 12288 + 4096 + (wc * 128 + n * 16 + lr) * 32 + ((lg ^ sw) * 8));
    };

    f32x4 acc[4][8] = {};
    stage(0, 0);
    stage(1, 1);
    asm volatile("s_waitcnt vmcnt(6)" ::: "memory");
    __builtin_amdgcn_s_barrier();

    int buf = 0;
    for (int t = 0; t < NT; ++t) {
        if (t + 2 < NT) {
            int nb = buf + 2; if (nb >= 3) nb -= 3;
            stage(nb, t + 2);
        }
        f16x8 a[4], b[8];
#pragma unroll
        for (int m = 0; m < 4; ++m) a[m] = LDA(buf, m);
#pragma unroll
        for (int n = 0; n < 8; ++n) b[n] = LDB(buf, n);
        __builtin_amdgcn_s_setprio(1);
#pragma unroll
        for (int m = 0; m < 4; ++m)
#pragma unroll
            for (int n = 0; n < 8; ++n)
                acc[m][n] = __builtin_amdgcn_mfma_f32_16x16x32_f16(a[m], b[n], acc[m][n], 0, 0, 0);
        __builtin_amdgcn_s_setprio(0);
        if (t + 2 < NT) {
            asm volatile("s_waitcnt vmcnt(6)" ::: "memory");
        } else if (t + 1 < NT) {
            asm volatile("s_waitcnt vmcnt(0)" ::: "memory");
        }
        __builtin_amdgcn_s_barrier();
        if (++buf >= 3) buf = 0;
    }
    // ---- epilogue
    if (MODE == 1) {
#pragma unroll
        for (int n = 0; n < 8; ++n) {
            const int col = n0 + wc * 128 + n * 16 + lr;
            const float bvv = b0[col];
#pragma unroll
            for (int m = 0; m < 4; ++m) {
                const int row = m0 + wr * 64 + m * 16 + lg * 4;
#pragma unroll
                for (int r = 0; r < 4; ++r)
                    Cout[(size_t)(row + r) * D_ + col] = acc[m][n][r] + bvv;
            }
        }
    } else {
        const float* bias = (seg == 0) ? b0 : (seg == 1) ? b1 : b2;
#pragma unroll
        for (int n = 0; n < 8; ++n) {
            const int lc = n0 + wc * 128 + n * 16 + lr; // 0..1023 within segment
            const float bvv = bias[lc];
#pragma unroll
            for (int m = 0; m < 4; ++m) {
                const int row = m0 + wr * 64 + m * 16 + lg * 4;
                if (seg == 2) { // V transposed: VT[B][H*HD][S]
                    const int bb = row >> 11, s0 = row & 2047;
                    f16x4 v;
#pragma unroll
                    for (int r = 0; r < 4; ++r) v[r] = (f16)(acc[m][n][r] + bvv);
                    *reinterpret_cast<f16x4*>(VtB + ((size_t)(bb * D_ + lc)) * S_ + s0) = v;
                } else {
                    f16* dst = seg ? Kb : Qb;
#pragma unroll
                    for (int r = 0; r < 4; ++r)
                        dst[(size_t)(row + r) * D_ + lc] = (f16)(acc[m][n][r] + bvv);
                }
            }
        }
    }
}

// ---------------------------------------------------------------- causal flash attention
// grid (H, B, 8), 256 threads = 4 waves. Block handles q-tiles {15-pp, pp}.
// K,V staged to LDS via global_load_lds, double-buffered, XOR-swizzled both sides.
// Counted vmcnt(4). Swapped QK^T; scale fused into exp FMA; defer-max.
// lsum via ones-MFMA: row-sums accumulate in the zacc layout (no VALU sum, no shfls).
__global__ __launch_bounds__(256, 2) void attn_kernel(const f16* __restrict__ Q,
                                                      const f16* __restrict__ Kg,
                                                      const f16* __restrict__ Vt,
                                                      f16* __restrict__ Z) {
    __shared__ __align__(16) f16 KL[2][64 * 64];
    __shared__ __align__(16) f16 VL[2][64 * 64];
    __shared__ __align__(16) f16 Pl[4][32][72];
    const int h = blockIdx.x, b = blockIdx.y, pp = blockIdx.z;
    const int tid = threadIdx.x, w = tid >> 6, l = tid & 63, lr = l & 15, lg = l >> 4;
    const size_t base   = ((size_t)b * S_) * D_ + h * HD_;
    const size_t vtbase = ((size_t)(b * D_ + h * HD_)) * S_;
    const f16* __restrict__ Kbase = Kg + base;
    const f16* __restrict__ Vbase = Vt + vtbase;
    const float sc = 0.125f * 1.44269504f; // 1/sqrt(64) * log2(e)
    const int sw_xor = lr & 7;
    f16x8 onesv;
#pragma unroll
    for (int i = 0; i < 8; ++i) onesv[i] = (f16)1.0f;

    auto stageKV = [&](int buf, int t0) {
#pragma unroll
        for (int i = 0; i < 2; ++i) {
            const int c = i * 256 + tid;
            const int row = c >> 3, g16 = (c & 7) ^ (row & 7);
            f16* dstK = &KL[buf][(i * 256 + w * 64) * 8];
            f16* dstV = &VL[buf][(i * 256 + w * 64) * 8];
            gload_lds16(Kbase + (size_t)(t0 + row) * D_ + g16 * 8, dstK);
            gload_lds16(Vbase + (size_t)row * S_ + t0 + g16 * 8, dstV);
        }
    };

    for (int half = 0; half < 2; ++half) {
        const int qt = half ? pp : (15 - pp);
        const int q0 = qt * 128, wq0 = q0 + w * 32;
        const int ntw = ((wq0 + 31) >> 6) + 1;
        const int ntb = qt * 2 + 2;

        f16x8 qf[2][2];
#pragma unroll
        for (int mf = 0; mf < 2; ++mf)
#pragma unroll
            for (int kd = 0; kd < 2; ++kd)
                qf[mf][kd] = *reinterpret_cast<const f16x8*>(
                    Q + base + (size_t)(wq0 + mf * 16 + lr) * D_ + kd * 32 + lg * 8);

        f32x4 zacc[2][4] = {};
        f32x4 lsv[2] = {};
        float mrun[2] = {-3.0e38f, -3.0e38f};

        stageKV(0, 0);
        for (int t = 0; t < ntb; ++t) {
            const int buf = t & 1;
            if (t + 1 < ntb) {
                stageKV(buf ^ 1, (t + 1) * 64);
                asm volatile("s_waitcnt vmcnt(4)" ::: "memory");
            } else {
                asm volatile("s_waitcnt vmcnt(0)" ::: "memory");
            }
            __builtin_amdgcn_s_barrier();
            if (t < ntw) {
                const int t0 = t * 64;
                f16x8 kf[2][4];
#pragma unroll
                for (int kd = 0; kd < 2; ++kd)
#pragma unroll
                    for (int n = 0; n < 4; ++n)
                        kf[kd][n] = *reinterpret_cast<const f16x8*>(
                            &KL[buf][(n * 16 + lr) * 64 + (((kd * 4 + lg) ^ sw_xor) * 8)]);
                f32x4 sf[2][4] = {};
                __builtin_amdgcn_s_setprio(1);
#pragma unroll
                for (int kd = 0; kd < 2; ++kd)
#pragma unroll
                    for (int n = 0; n < 4; ++n)
#pragma unroll
                        for (int mf = 0; mf < 2; ++mf)
                            sf[mf][n] = __builtin_amdgcn_mfma_f32_16x16x32_f16(kf[kd][n], qf[mf][kd], sf[mf][n], 0, 0, 0);
                __builtin_amdgcn_s_setprio(0);
                f16x8 vf[2][4];
#pragma unroll
                for (int kt = 0; kt < 2; ++kt)
#pragma unroll
                    for (int n = 0; n < 4; ++n)
                        vf[kt][n] = *reinterpret_cast<const f16x8*>(
                            &VL[buf][(n * 16 + lr) * 64 + (((kt * 4 + lg) ^ sw_xor) * 8)]);
                if (t == ntw - 1) {
#pragma unroll
                    for (int mf = 0; mf < 2; ++mf)
#pragma unroll
                        for (int n = 0; n < 4; ++n)
#pragma unroll
                            for (int r = 0; r < 4; ++r)
                                if ((t0 + n * 16 + lg * 4 + r) > (wq0 + mf * 16 + lr))
                                    sf[mf][n][r] = -3.0e38f;
                }
#pragma unroll
                for (int mf = 0; mf < 2; ++mf) {
                    f32x4 t4;
#pragma unroll
                    for (int r = 0; r < 4; ++r)
                        t4[r] = fmaxf(fmaxf(sf[mf][0][r], sf[mf][1][r]), fmaxf(sf[mf][2][r], sf[mf][3][r]));
                    float vmax = fmaxf(fmaxf(t4[0], t4[1]), fmaxf(t4[2], t4[3]));
                    vmax = fmaxf(vmax, __shfl_xor(vmax, 16));
                    vmax = fmaxf(vmax, __shfl_xor(vmax, 32));
                    const float vs = vmax * sc;
                    const bool norm = !__all(vs <= mrun[mf] + 10.0f);
                    if (norm) {
                        const float mnew = fmaxf(mrun[mf], vs);
                        const float al = __builtin_amdgcn_exp2f(mrun[mf] - mnew);
                        mrun[mf] = mnew;
#pragma unroll
                        for (int r = 0; r < 4; ++r) {
                            const float ar = __shfl(al, lg * 4 + r);
#pragma unroll
                            for (int n = 0; n < 4; ++n) zacc[mf][n][r] *= ar;
                            lsv[mf][r] *= ar;
                        }
                    }
#pragma unroll
                    for (int n = 0; n < 4; ++n) {
                        f32x4 p;
#pragma unroll
                        for (int r = 0; r < 4; ++r)
                            p[r] = __builtin_amdgcn_exp2f(fmaf(sf[mf][n][r], sc, -mrun[mf]));
                        f16x4 pv;
#pragma unroll
                        for (int r = 0; r < 4; ++r) pv[r] = (f16)p[r];
                        *reinterpret_cast<f16x4*>(&Pl[w][mf * 16 + lr][n * 16 + lg * 4]) = pv;
                    }
                }
#pragma unroll
                for (int kt = 0; kt < 2; ++kt) {
                    f16x8 pa[2];
#pragma unroll
                    for (int mf = 0; mf < 2; ++mf)
                        pa[mf] = *reinterpret_cast<const f16x8*>(&Pl[w][mf * 16 + lr][kt * 32 + lg * 8]);
                    __builtin_amdgcn_s_setprio(1);
#pragma unroll
                    for (int n = 0; n < 4; ++n)
#pragma unroll
                        for (int mf = 0; mf < 2; ++mf)
                            zacc[mf][n] = __builtin_amdgcn_mfma_f32_16x16x32_f16(pa[mf], vf[kt][n], zacc[mf][n], 0, 0, 0);
#pragma unroll
                    for (int mf = 0; mf < 2; ++mf)
                        lsv[mf] = __builtin_amdgcn_mfma_f32_16x16x32_f16(pa[mf], onesv, lsv[mf], 0, 0, 0);
                    __builtin_amdgcn_s_setprio(0);
                }
            }
            __builtin_amdgcn_s_barrier();
        }
#pragma unroll
        for (int mf = 0; mf < 2; ++mf) {
            f32x4 inv;
#pragma unroll
            for (int r = 0; r < 4; ++r) inv[r] = 1.0f / lsv[mf][r];
#pragma unroll
            for (int r = 0; r < 4; ++r)
#pragma unroll
                for (int n = 0; n < 4; ++n)
                    Z[base + (size_t)(wq0 + mf * 16 + lg * 4 + r) * D_ + n * 16 + lr] =
                        (f16)(zacc[mf][n][r] * inv[r]);
        }
    }
}

// ---------------------------------------------------------------- launcher
extern "C" void kernel_launch(void* const* d_in, const int* in_sizes, int n_in,
                              void* d_out, int out_size, void* d_ws, size_t ws_size,
                              hipStream_t stream) {
    const float* data    = (const float*)d_in[0];
    const float* context = (const float*)d_in[1];
    const float* Wq = (const float*)d_in[2];
    const float* bq = (const float*)d_in[3];
    const float* Wk = (const float*)d_in[4];
    const float* bk = (const float*)d_in[5];
    const float* Wv = (const float*)d_in[6];
    const float* bv = (const float*)d_in[7];
    const float* Wo = (const float*)d_in[8];
    const float* bo = (const float*)d_in[9];

    const size_t MD = (size_t)M_ * D_;
    const size_t DD = (size_t)D_ * D_;
    f16* dataB = (f16*)d_ws;
    f16* ctxB  = dataB + MD;
    f16* WqT   = ctxB + MD;   // WqT,WkT,WvT,WoT contiguous
    f16* WkT   = WqT + DD;
    f16* WvT   = WkT + DD;
    f16* WoT   = WvT + DD;
    f16* Qb    = WoT + DD;
    f16* Kb    = Qb + MD;
    f16* VtB   = Kb + MD;     // [B][H][HD][S]
    f16* Zb    = VtB + MD;

    (void)WkT; (void)WvT;

    const int n4 = (int)(MD / 4);
    cvt2_kernel<<<2048, 256, 0, stream>>>(data, context, dataB, n4);
    transpose_cvt4_kernel<<<dim3(32, 32, 4), 256, 0, stream>>>(Wq, Wk, Wv, Wo, WqT);

    (void)hipFuncSetAttribute(reinterpret_cast<const void*>(gemm3p<0>),
                              hipFuncAttributeMaxDynamicSharedMemorySize, 73728);
    (void)hipFuncSetAttribute(reinterpret_cast<const void*>(gemm3p<1>),
                              hipFuncAttributeMaxDynamicSharedMemorySize, 73728);

    // QKV as 3 SEPARATE dispatches -> true temporal L2 isolation per segment
    gemm3p<0><<<256, 256, 73728, stream>>>(dataB, ctxB, WqT, bq, bk, bv,
                                           Qb, Kb, VtB, nullptr, 0);
    gemm3p<0><<<256, 256, 73728, stream>>>(dataB, ctxB, WqT, bq, bk, bv,
                                           Qb, Kb, VtB, nullptr, 1);
    gemm3p<0><<<256, 256, 73728, stream>>>(dataB, ctxB, WqT, bq, bk, bv,
                                           Qb, Kb, VtB, nullptr, 2);

    attn_kernel<<<dim3(H_, B_, 8), 256, 0, stream>>>(Qb, Kb, VtB, Zb);

    // output GEMM: A=Zb, B=WoT, bias=bo
    gemm3p<1><<<256, 256, 73728, stream>>>(Zb, nullptr, WoT, bo, nullptr, nullptr,
                                           nullptr, nullptr, nullptr, (float*)d_out, 0);
}

// Round 18
// 167.128 us; speedup vs baseline: 1.1086x; 1.1086x over previous
//
#include <hip/hip_runtime.h>

// Problem constants
#define B_  4
#define S_  2048
#define D_  1024
#define H_  16
#define HD_ 64
#define M_  (B_*S_)   // 8192 rows total

typedef _Float16 f16;
typedef f16  f16x8 __attribute__((ext_vector_type(8)));
typedef f16  f16x4 __attribute__((ext_vector_type(4)));
typedef float f32x4 __attribute__((ext_vector_type(4)));

// global -> LDS direct DMA, 16B per lane. LDS dest = wave-uniform base + lane*16.
__device__ __forceinline__ void gload_lds16(const f16* g, f16* l) {
    __builtin_amdgcn_global_load_lds(
        (const __attribute__((address_space(1))) void*)g,
        (__attribute__((address_space(3))) void*)l, 16, 0, 0);
}

// all four weights W[K][N] f32 -> WT[N][K] f16 (outputs contiguous per z)
__global__ __launch_bounds__(256) void transpose_cvt4_kernel(const float* __restrict__ Wq,
                                                             const float* __restrict__ Wk,
                                                             const float* __restrict__ Wv,
                                                             const float* __restrict__ Wo,
                                                             f16* __restrict__ WT) {
    __shared__ float tile[32][33];
    const int z = blockIdx.z;
    const float* W = (z == 0) ? Wq : (z == 1) ? Wk : (z == 2) ? Wv : Wo;
    f16* dst = WT + (size_t)z * D_ * D_;
    const int n0 = blockIdx.x * 32, k0 = blockIdx.y * 32;
    const int tx = threadIdx.x & 31, ty = threadIdx.x >> 5; // (32,8)
#pragma unroll
    for (int j = 0; j < 4; ++j)
        tile[ty + 8 * j][tx] = W[(size_t)(k0 + ty + 8 * j) * D_ + n0 + tx];
    __syncthreads();
#pragma unroll
    for (int j = 0; j < 4; ++j)
        dst[(size_t)(n0 + ty + 8 * j) * D_ + k0 + tx] = (f16)tile[tx][ty + 8 * j];
}

// ---------------------------------------------------------------- fused QKV GEMM with inline f32->f16 A-convert
// BM=128 x BN=256, BK=32, 256 threads = 4 waves (2M x 2N); per-wave 64x128 out.
// A read DIRECTLY from f32 inputs (no cvt pass): reg-staged 4x dwordx4 -> cvt ->
// 2x ds_write_b128. B via gload_lds DMA. Triple-buffered LDS (72KB), depth-2
// staging, counted vmcnt(8) = exactly tile t+1's 8 events (4 A-ret + 4 B-DMA),
// tile t+2's 8 stay in flight. lgkmcnt(0) publishes A-writes before barrier.
// 768 blocks = 3 seq segments by id>>8 (r16 best config), XCD-chunked remap.
__global__ __launch_bounds__(256, 2) void gemm_qkvf(const float* __restrict__ Fa,
                                                    const float* __restrict__ Fc,
                                                    const f16* __restrict__ Wbase,
                                                    const float* __restrict__ b0,
                                                    const float* __restrict__ b1,
                                                    const float* __restrict__ b2,
                                                    f16* __restrict__ Qb,
                                                    f16* __restrict__ Kb,
                                                    f16* __restrict__ VtB) {
    extern __shared__ __align__(16) f16 SM[]; // 3 x 12288 f16 (A 4096 + B 8192 each)
    constexpr int K = D_;
    constexpr int NT = K / 32; // 32
    const int id = (int)blockIdx.x;
    const int seg = id >> 8;                       // 0=Q,1=K,2=V
    const int sid = id & 255;
    const int work = (sid & 7) * 32 + (sid >> 3);  // XCD-chunked, bijective
    const int wy = work >> 2, wx = work & 3;       // 64 x 4
    const float* __restrict__ Af = seg ? Fc : Fa;
    const f16* __restrict__ Wt = Wbase + (size_t)seg * D_ * D_;
    const int m0 = wy * 128, n0 = wx * 256;
    const int tid = (int)threadIdx.x;
    const int w = tid >> 6, lr = tid & 15, lg = (tid & 63) >> 4;
    const int wr = w >> 1, wc = w & 1;
    const int sw = (lr >> 1) & 3;
    // A reg-staging geometry: thread owns chunks 2*tid, 2*tid+1 (row = tid>>1)
    const int arow = tid >> 1;
    const int s0g = (2 * (tid & 1)) ^ ((arow >> 1) & 3); // pre-swizzled global slot
    const int s1g = s0g ^ 1;
    const float* __restrict__ Abase = Af + (size_t)(m0 + arow) * K;

    auto stageB = [&](int buf, int kt) {
        const int kk0 = kt * 32;
#pragma unroll
        for (int j = 0; j < 4; ++j) {
            const int c = j * 256 + tid;
            const int row = c >> 2;
            const int ks = ((c & 3) ^ ((row >> 1) & 3)) * 8;
            gload_lds16(Wt + (size_t)(n0 + row) * K + kk0 + ks,
                        SM + buf * 12288 + 4096 + (j * 256 + w * 64) * 8);
        }
    };
    auto LDA = [&](int buf, int m) -> f16x8 {
        return *reinterpret_cast<const f16x8*>(
            SM + buf * 12288 + (wr * 64 + m * 16 + lr) * 32 + ((lg ^ sw) * 8));
    };
    auto LDB = [&](int buf, int n) -> f16x8 {
        return *reinterpret_cast<const f16x8*>(
            SM + buf * 12288 + 4096 + (wc * 128 + n * 16 + lr) * 32 + ((lg ^ sw) * 8));
    };

    f32x4 rA0[4], rA1[4];
    f32x4 acc[4][8] = {};

#define LOAD_A(RS, KT)                                                          \
    {                                                                           \
        const float* ap_ = Abase + (KT) * 32;                                   \
        RS[0] = *reinterpret_cast<const f32x4*>(ap_ + s0g * 8);                 \
        RS[1] = *reinterpret_cast<const f32x4*>(ap_ + s0g * 8 + 4);             \
        RS[2] = *reinterpret_cast<const f32x4*>(ap_ + s1g * 8);                 \
        RS[3] = *reinterpret_cast<const f32x4*>(ap_ + s1g * 8 + 4);             \
    }
#define WRITE_A(RS, BUF)                                                        \
    {                                                                           \
        f16* ad_ = SM + (BUF) * 12288 + tid * 16;                               \
        *reinterpret_cast<f16x8*>(ad_) = __builtin_shufflevector(               \
            __builtin_convertvector(RS[0], f16x4),                              \
            __builtin_convertvector(RS[1], f16x4), 0, 1, 2, 3, 4, 5, 6, 7);     \
        *reinterpret_cast<f16x8*>(ad_ + 8) = __builtin_shufflevector(           \
            __builtin_convertvector(RS[2], f16x4),                              \
            __builtin_convertvector(RS[3], f16x4), 0, 1, 2, 3, 4, 5, 6, 7);     \
    }
#define TILE_BODY(T, RISS, RWR)                                                 \
    {                                                                           \
        const int buf_ = (T) % 3;                                               \
        if ((T) + 2 < NT) {                                                     \
            LOAD_A(RISS, (T) + 2);                                              \
            stageB(((T) + 2) % 3, (T) + 2);                                     \
            asm volatile("" ::: "memory");                                      \
        }                                                                       \
        f16x8 a_[4], b_[8];                                                     \
        _Pragma("unroll") for (int m = 0; m < 4; ++m) a_[m] = LDA(buf_, m);     \
        _Pragma("unroll") for (int n = 0; n < 8; ++n) b_[n] = LDB(buf_, n);     \
        __builtin_amdgcn_s_setprio(1);                                          \
        _Pragma("unroll") for (int m = 0; m < 4; ++m)                           \
            _Pragma("unroll") for (int n = 0; n < 8; ++n)                       \
                acc[m][n] = __builtin_amdgcn_mfma_f32_16x16x32_f16(             \
                    a_[m], b_[n], acc[m][n], 0, 0, 0);                          \
        __builtin_amdgcn_s_setprio(0);                                          \
        if ((T) + 1 < NT) {                                                     \
            if ((T) + 2 < NT) { asm volatile("s_waitcnt vmcnt(8)" ::: "memory"); } \
            else              { asm volatile("s_waitcnt vmcnt(0)" ::: "memory"); } \
            WRITE_A(RWR, ((T) + 1) % 3);                                        \
            asm volatile("s_waitcnt lgkmcnt(0)" ::: "memory");                  \
            __builtin_amdgcn_s_barrier();                                       \
        }                                                                       \
    }

    // prologue: A(0)->rA0, B(0); A(1)->rA1, B(1); wait A0+B0; publish A0
    LOAD_A(rA0, 0);
    stageB(0, 0);
    asm volatile("" ::: "memory");
    LOAD_A(rA1, 1);
    stageB(1, 1);
    asm volatile("s_waitcnt vmcnt(8)" ::: "memory");
    WRITE_A(rA0, 0);
    asm volatile("s_waitcnt lgkmcnt(0)" ::: "memory");
    __builtin_amdgcn_s_barrier();

    int t = 0;
    for (; t < NT - 2; t += 2) {
        TILE_BODY(t,     rA0, rA1);
        TILE_BODY(t + 1, rA1, rA0);
    }
    TILE_BODY(NT - 2, rA0, rA1); // no issue; vmcnt(0); publish A(31)
    TILE_BODY(NT - 1, rA1, rA0); // compute only
#undef TILE_BODY
#undef WRITE_A
#undef LOAD_A

    // ---- epilogue
    const float* bias = (seg == 0) ? b0 : (seg == 1) ? b1 : b2;
#pragma unroll
    for (int n = 0; n < 8; ++n) {
        const int lc = n0 + wc * 128 + n * 16 + lr; // 0..1023 within segment
        const float bvv = bias[lc];
#pragma unroll
        for (int m = 0; m < 4; ++m) {
            const int row = m0 + wr * 64 + m * 16 + lg * 4;
            if (seg == 2) { // V transposed: VT[B][H*HD][S]
                const int bb = row >> 11, s0 = row & 2047;
                f16x4 v;
#pragma unroll
                for (int r = 0; r < 4; ++r) v[r] = (f16)(acc[m][n][r] + bvv);
                *reinterpret_cast<f16x4*>(VtB + ((size_t)(bb * D_ + lc)) * S_ + s0) = v;
            } else {
                f16* dst = seg ? Kb : Qb;
#pragma unroll
                for (int r = 0; r < 4; ++r)
                    dst[(size_t)(row + r) * D_ + lc] = (f16)(acc[m][n][r] + bvv);
            }
        }
    }
}

// ---------------------------------------------------------------- output GEMM, triple-buffered (r16-verified)
// BM=128 x BN=256, BK=32, 256 threads; 256 blocks. Depth-2 staging, vmcnt(6).
__global__ __launch_bounds__(256, 2) void gemm_out3(const f16* __restrict__ A,
                                                    const f16* __restrict__ Wt,
                                                    const float* __restrict__ bias,
                                                    float* __restrict__ Cout) {
    extern __shared__ __align__(16) f16 SM[];
    constexpr int K = D_;
    constexpr int NT = K / 32;
    const int id = (int)blockIdx.x;
    const int work = (id & 7) * 32 + (id >> 3);
    const int wy = work >> 2, wx = work & 3;
    const int m0 = wy * 128, n0 = wx * 256;
    const int tid = (int)threadIdx.x;
    const int w = tid >> 6, lr = tid & 15, lg = (tid & 63) >> 4;
    const int wr = w >> 1, wc = w & 1;
    const int sw = (lr >> 1) & 3;

    auto stage = [&](int buf, int kt) {
        const int kk0 = kt * 32;
        f16* base = SM + buf * 12288;
#pragma unroll
        for (int j = 0; j < 2; ++j) {
            const int c = j * 256 + tid;
            const int row = c >> 2;
            const int ks = ((c & 3) ^ ((row >> 1) & 3)) * 8;
            gload_lds16(A + (size_t)(m0 + row) * K + kk0 + ks,
                        base + (j * 256 + w * 64) * 8);
        }
#pragma unroll
        for (int j = 0; j < 4; ++j) {
            const int c = j * 256 + tid;
            const int row = c >> 2;
            const int ks = ((c & 3) ^ ((row >> 1) & 3)) * 8;
            gload_lds16(Wt + (size_t)(n0 + row) * K + kk0 + ks,
                        base + 4096 + (j * 256 + w * 64) * 8);
        }
    };
    auto LDA = [&](int buf, int m) -> f16x8 {
        return *reinterpret_cast<const f16x8*>(
            SM + buf * 12288 + (wr * 64 + m * 16 + lr) * 32 + ((lg ^ sw) * 8));
    };
    auto LDB = [&](int buf, int n) -> f16x8 {
        return *reinterpret_cast<const f16x8*>(
            SM + buf * 12288 + 4096 + (wc * 128 + n * 16 + lr) * 32 + ((lg ^ sw) * 8));
    };

    f32x4 acc[4][8] = {};
    stage(0, 0);
    stage(1, 1);
    asm volatile("s_waitcnt vmcnt(6)" ::: "memory");
    __builtin_amdgcn_s_barrier();

    int buf = 0;
    for (int t = 0; t < NT; ++t) {
        if (t + 2 < NT) {
            int nb = buf + 2; if (nb >= 3) nb -= 3;
            stage(nb, t + 2);
        }
        f16x8 a[4], b[8];
#pragma unroll
        for (int m = 0; m < 4; ++m) a[m] = LDA(buf, m);
#pragma unroll
        for (int n = 0; n < 8; ++n) b[n] = LDB(buf, n);
        __builtin_amdgcn_s_setprio(1);
#pragma unroll
        for (int m = 0; m < 4; ++m)
#pragma unroll
            for (int n = 0; n < 8; ++n)
                acc[m][n] = __builtin_amdgcn_mfma_f32_16x16x32_f16(a[m], b[n], acc[m][n], 0, 0, 0);
        __builtin_amdgcn_s_setprio(0);
        if (t + 2 < NT) {
            asm volatile("s_waitcnt vmcnt(6)" ::: "memory");
        } else if (t + 1 < NT) {
            asm volatile("s_waitcnt vmcnt(0)" ::: "memory");
        }
        __builtin_amdgcn_s_barrier();
        if (++buf >= 3) buf = 0;
    }
#pragma unroll
    for (int n = 0; n < 8; ++n) {
        const int col = n0 + wc * 128 + n * 16 + lr;
        const float bvv = bias[col];
#pragma unroll
        for (int m = 0; m < 4; ++m) {
            const int row = m0 + wr * 64 + m * 16 + lg * 4;
#pragma unroll
            for (int r = 0; r < 4; ++r)
                Cout[(size_t)(row + r) * D_ + col] = acc[m][n][r] + bvv;
        }
    }
}

// ---------------------------------------------------------------- causal flash attention (r16-verified, frozen)
__global__ __launch_bounds__(256, 2) void attn_kernel(const f16* __restrict__ Q,
                                                      const f16* __restrict__ Kg,
                                                      const f16* __restrict__ Vt,
                                                      f16* __restrict__ Z) {
    __shared__ __align__(16) f16 KL[2][64 * 64];
    __shared__ __align__(16) f16 VL[2][64 * 64];
    __shared__ __align__(16) f16 Pl[4][32][72];
    const int h = blockIdx.x, b = blockIdx.y, pp = blockIdx.z;
    const int tid = threadIdx.x, w = tid >> 6, l = tid & 63, lr = l & 15, lg = l >> 4;
    const size_t base   = ((size_t)b * S_) * D_ + h * HD_;
    const size_t vtbase = ((size_t)(b * D_ + h * HD_)) * S_;
    const f16* __restrict__ Kbase = Kg + base;
    const f16* __restrict__ Vbase = Vt + vtbase;
    const float sc = 0.125f * 1.44269504f; // 1/sqrt(64) * log2(e)
    const int sw_xor = lr & 7;
    f16x8 onesv;
#pragma unroll
    for (int i = 0; i < 8; ++i) onesv[i] = (f16)1.0f;

    auto stageKV = [&](int buf, int t0) {
#pragma unroll
        for (int i = 0; i < 2; ++i) {
            const int c = i * 256 + tid;
            const int row = c >> 3, g16 = (c & 7) ^ (row & 7);
            f16* dstK = &KL[buf][(i * 256 + w * 64) * 8];
            f16* dstV = &VL[buf][(i * 256 + w * 64) * 8];
            gload_lds16(Kbase + (size_t)(t0 + row) * D_ + g16 * 8, dstK);
            gload_lds16(Vbase + (size_t)row * S_ + t0 + g16 * 8, dstV);
        }
    };

    for (int half = 0; half < 2; ++half) {
        const int qt = half ? pp : (15 - pp);
        const int q0 = qt * 128, wq0 = q0 + w * 32;
        const int ntw = ((wq0 + 31) >> 6) + 1;
        const int ntb = qt * 2 + 2;

        f16x8 qf[2][2];
#pragma unroll
        for (int mf = 0; mf < 2; ++mf)
#pragma unroll
            for (int kd = 0; kd < 2; ++kd)
                qf[mf][kd] = *reinterpret_cast<const f16x8*>(
                    Q + base + (size_t)(wq0 + mf * 16 + lr) * D_ + kd * 32 + lg * 8);

        f32x4 zacc[2][4] = {};
        f32x4 lsv[2] = {};
        float mrun[2] = {-3.0e38f, -3.0e38f};

        stageKV(0, 0);
        for (int t = 0; t < ntb; ++t) {
            const int buf = t & 1;
            if (t + 1 < ntb) {
                stageKV(buf ^ 1, (t + 1) * 64);
                asm volatile("s_waitcnt vmcnt(4)" ::: "memory");
            } else {
                asm volatile("s_waitcnt vmcnt(0)" ::: "memory");
            }
            __builtin_amdgcn_s_barrier();
            if (t < ntw) {
                const int t0 = t * 64;
                f16x8 kf[2][4];
#pragma unroll
                for (int kd = 0; kd < 2; ++kd)
#pragma unroll
                    for (int n = 0; n < 4; ++n)
                        kf[kd][n] = *reinterpret_cast<const f16x8*>(
                            &KL[buf][(n * 16 + lr) * 64 + (((kd * 4 + lg) ^ sw_xor) * 8)]);
                f32x4 sf[2][4] = {};
                __builtin_amdgcn_s_setprio(1);
#pragma unroll
                for (int kd = 0; kd < 2; ++kd)
#pragma unroll
                    for (int n = 0; n < 4; ++n)
#pragma unroll
                        for (int mf = 0; mf < 2; ++mf)
                            sf[mf][n] = __builtin_amdgcn_mfma_f32_16x16x32_f16(kf[kd][n], qf[mf][kd], sf[mf][n], 0, 0, 0);
                __builtin_amdgcn_s_setprio(0);
                f16x8 vf[2][4];
#pragma unroll
                for (int kt = 0; kt < 2; ++kt)
#pragma unroll
                    for (int n = 0; n < 4; ++n)
                        vf[kt][n] = *reinterpret_cast<const f16x8*>(
                            &VL[buf][(n * 16 + lr) * 64 + (((kt * 4 + lg) ^ sw_xor) * 8)]);
                if (t == ntw - 1) {
#pragma unroll
                    for (int mf = 0; mf < 2; ++mf)
#pragma unroll
                        for (int n = 0; n < 4; ++n)
#pragma unroll
                            for (int r = 0; r < 4; ++r)
                                if ((t0 + n * 16 + lg * 4 + r) > (wq0 + mf * 16 + lr))
                                    sf[mf][n][r] = -3.0e38f;
                }
#pragma unroll
                for (int mf = 0; mf < 2; ++mf) {
                    f32x4 t4;
#pragma unroll
                    for (int r = 0; r < 4; ++r)
                        t4[r] = fmaxf(fmaxf(sf[mf][0][r], sf[mf][1][r]), fmaxf(sf[mf][2][r], sf[mf][3][r]));
                    float vmax = fmaxf(fmaxf(t4[0], t4[1]), fmaxf(t4[2], t4[3]));
                    vmax = fmaxf(vmax, __shfl_xor(vmax, 16));
                    vmax = fmaxf(vmax, __shfl_xor(vmax, 32));
                    const float vs = vmax * sc;
                    const bool norm = !__all(vs <= mrun[mf] + 10.0f);
                    if (norm) {
                        const float mnew = fmaxf(mrun[mf], vs);
                        const float al = __builtin_amdgcn_exp2f(mrun[mf] - mnew);
                        mrun[mf] = mnew;
#pragma unroll
                        for (int r = 0; r < 4; ++r) {
                            const float ar = __shfl(al, lg * 4 + r);
#pragma unroll
                            for (int n = 0; n < 4; ++n) zacc[mf][n][r] *= ar;
                            lsv[mf][r] *= ar;
                        }
                    }
#pragma unroll
                    for (int n = 0; n < 4; ++n) {
                        f32x4 p;
#pragma unroll
                        for (int r = 0; r < 4; ++r)
                            p[r] = __builtin_amdgcn_exp2f(fmaf(sf[mf][n][r], sc, -mrun[mf]));
                        f16x4 pv;
#pragma unroll
                        for (int r = 0; r < 4; ++r) pv[r] = (f16)p[r];
                        *reinterpret_cast<f16x4*>(&Pl[w][mf * 16 + lr][n * 16 + lg * 4]) = pv;
                    }
                }
#pragma unroll
                for (int kt = 0; kt < 2; ++kt) {
                    f16x8 pa[2];
#pragma unroll
                    for (int mf = 0; mf < 2; ++mf)
                        pa[mf] = *reinterpret_cast<const f16x8*>(&Pl[w][mf * 16 + lr][kt * 32 + lg * 8]);
                    __builtin_amdgcn_s_setprio(1);
#pragma unroll
                    for (int n = 0; n < 4; ++n)
#pragma unroll
                        for (int mf = 0; mf < 2; ++mf)
                            zacc[mf][n] = __builtin_amdgcn_mfma_f32_16x16x32_f16(pa[mf], vf[kt][n], zacc[mf][n], 0, 0, 0);
#pragma unroll
                    for (int mf = 0; mf < 2; ++mf)
                        lsv[mf] = __builtin_amdgcn_mfma_f32_16x16x32_f16(pa[mf], onesv, lsv[mf], 0, 0, 0);
                    __builtin_amdgcn_s_setprio(0);
                }
            }
            __builtin_amdgcn_s_barrier();
        }
#pragma unroll
        for (int mf = 0; mf < 2; ++mf) {
            f32x4 inv;
#pragma unroll
            for (int r = 0; r < 4; ++r) inv[r] = 1.0f / lsv[mf][r];
#pragma unroll
            for (int r = 0; r < 4; ++r)
#pragma unroll
                for (int n = 0; n < 4; ++n)
                    Z[base + (size_t)(wq0 + mf * 16 + lg * 4 + r) * D_ + n * 16 + lr] =
                        (f16)(zacc[mf][n][r] * inv[r]);
        }
    }
}

// ---------------------------------------------------------------- launcher
extern "C" void kernel_launch(void* const* d_in, const int* in_sizes, int n_in,
                              void* d_out, int out_size, void* d_ws, size_t ws_size,
                              hipStream_t stream) {
    const float* data    = (const float*)d_in[0];
    const float* context = (const float*)d_in[1];
    const float* Wq = (const float*)d_in[2];
    const float* bq = (const float*)d_in[3];
    const float* Wk = (const float*)d_in[4];
    const float* bk = (const float*)d_in[5];
    const float* Wv = (const float*)d_in[6];
    const float* bv = (const float*)d_in[7];
    const float* Wo = (const float*)d_in[8];
    const float* bo = (const float*)d_in[9];

    const size_t MD = (size_t)M_ * D_;
    const size_t DD = (size_t)D_ * D_;
    f16* WqT   = (f16*)d_ws;  // WqT,WkT,WvT,WoT contiguous
    f16* WoT   = WqT + 3 * DD;
    f16* Qb    = WqT + 4 * DD;
    f16* Kb    = Qb + MD;
    f16* VtB   = Kb + MD;     // [B][H][HD][S]
    f16* Zb    = VtB + MD;

    transpose_cvt4_kernel<<<dim3(32, 32, 4), 256, 0, stream>>>(Wq, Wk, Wv, Wo, WqT);

    (void)hipFuncSetAttribute(reinterpret_cast<const void*>(gemm_qkvf),
                              hipFuncAttributeMaxDynamicSharedMemorySize, 73728);
    (void)hipFuncSetAttribute(reinterpret_cast<const void*>(gemm_out3),
                              hipFuncAttributeMaxDynamicSharedMemorySize, 73728);

    // fused QKV: reads f32 data/context directly (cvt pass eliminated)
    gemm_qkvf<<<768, 256, 73728, stream>>>(data, context, WqT, bq, bk, bv,
                                           Qb, Kb, VtB);

    attn_kernel<<<dim3(H_, B_, 8), 256, 0, stream>>>(Qb, Kb, VtB, Zb);

    gemm_out3<<<256, 256, 73728, stream>>>(Zb, WoT, bo, (float*)d_out);
}

// Round 19
// 159.675 us; speedup vs baseline: 1.1604x; 1.0467x over previous
//
#include <hip/hip_runtime.h>

// Problem constants
#define B_  4
#define S_  2048
#define D_  1024
#define H_  16
#define HD_ 64
#define M_  (B_*S_)   // 8192 rows total

typedef _Float16 f16;
typedef f16  f16x8 __attribute__((ext_vector_type(8)));
typedef f16  f16x4 __attribute__((ext_vector_type(4)));
typedef float f32x4 __attribute__((ext_vector_type(4)));

// global -> LDS direct DMA, 16B per lane. LDS dest = wave-uniform base + lane*16.
__device__ __forceinline__ void gload_lds16(const f16* g, f16* l) {
    __builtin_amdgcn_global_load_lds(
        (const __attribute__((address_space(1))) void*)g,
        (__attribute__((address_space(3))) void*)l, 16, 0, 0);
}

// all four weights W[K][N] f32 -> WT[N][K] f16 (outputs contiguous per z)
__global__ __launch_bounds__(256) void transpose_cvt4_kernel(const float* __restrict__ Wq,
                                                             const float* __restrict__ Wk,
                                                             const float* __restrict__ Wv,
                                                             const float* __restrict__ Wo,
                                                             f16* __restrict__ WT) {
    __shared__ float tile[32][33];
    const int z = blockIdx.z;
    const float* W = (z == 0) ? Wq : (z == 1) ? Wk : (z == 2) ? Wv : Wo;
    f16* dst = WT + (size_t)z * D_ * D_;
    const int n0 = blockIdx.x * 32, k0 = blockIdx.y * 32;
    const int tx = threadIdx.x & 31, ty = threadIdx.x >> 5; // (32,8)
#pragma unroll
    for (int j = 0; j < 4; ++j)
        tile[ty + 8 * j][tx] = W[(size_t)(k0 + ty + 8 * j) * D_ + n0 + tx];
    __syncthreads();
#pragma unroll
    for (int j = 0; j < 4; ++j)
        dst[(size_t)(n0 + ty + 8 * j) * D_ + k0 + tx] = (f16)tile[tx][ty + 8 * j];
}

// ---------------------------------------------------------------- fused QKV GEMM with inline f32->f16 A-convert
// (r18 measured config — frozen)
__global__ __launch_bounds__(256, 2) void gemm_qkvf(const float* __restrict__ Fa,
                                                    const float* __restrict__ Fc,
                                                    const f16* __restrict__ Wbase,
                                                    const float* __restrict__ b0,
                                                    const float* __restrict__ b1,
                                                    const float* __restrict__ b2,
                                                    f16* __restrict__ Qb,
                                                    f16* __restrict__ Kb,
                                                    f16* __restrict__ VtB) {
    extern __shared__ __align__(16) f16 SM[]; // 3 x 12288 f16 (A 4096 + B 8192 each)
    constexpr int K = D_;
    constexpr int NT = K / 32; // 32
    const int id = (int)blockIdx.x;
    const int seg = id >> 8;                       // 0=Q,1=K,2=V
    const int sid = id & 255;
    const int work = (sid & 7) * 32 + (sid >> 3);  // XCD-chunked, bijective
    const int wy = work >> 2, wx = work & 3;       // 64 x 4
    const float* __restrict__ Af = seg ? Fc : Fa;
    const f16* __restrict__ Wt = Wbase + (size_t)seg * D_ * D_;
    const int m0 = wy * 128, n0 = wx * 256;
    const int tid = (int)threadIdx.x;
    const int w = tid >> 6, lr = tid & 15, lg = (tid & 63) >> 4;
    const int wr = w >> 1, wc = w & 1;
    const int sw = (lr >> 1) & 3;
    const int arow = tid >> 1;
    const int s0g = (2 * (tid & 1)) ^ ((arow >> 1) & 3); // pre-swizzled global slot
    const int s1g = s0g ^ 1;
    const float* __restrict__ Abase = Af + (size_t)(m0 + arow) * K;

    auto stageB = [&](int buf, int kt) {
        const int kk0 = kt * 32;
#pragma unroll
        for (int j = 0; j < 4; ++j) {
            const int c = j * 256 + tid;
            const int row = c >> 2;
            const int ks = ((c & 3) ^ ((row >> 1) & 3)) * 8;
            gload_lds16(Wt + (size_t)(n0 + row) * K + kk0 + ks,
                        SM + buf * 12288 + 4096 + (j * 256 + w * 64) * 8);
        }
    };
    auto LDA = [&](int buf, int m) -> f16x8 {
        return *reinterpret_cast<const f16x8*>(
            SM + buf * 12288 + (wr * 64 + m * 16 + lr) * 32 + ((lg ^ sw) * 8));
    };
    auto LDB = [&](int buf, int n) -> f16x8 {
        return *reinterpret_cast<const f16x8*>(
            SM + buf * 12288 + 4096 + (wc * 128 + n * 16 + lr) * 32 + ((lg ^ sw) * 8));
    };

    f32x4 rA0[4], rA1[4];
    f32x4 acc[4][8] = {};

#define LOAD_A(RS, KT)                                                          \
    {                                                                           \
        const float* ap_ = Abase + (KT) * 32;                                   \
        RS[0] = *reinterpret_cast<const f32x4*>(ap_ + s0g * 8);                 \
        RS[1] = *reinterpret_cast<const f32x4*>(ap_ + s0g * 8 + 4);             \
        RS[2] = *reinterpret_cast<const f32x4*>(ap_ + s1g * 8);                 \
        RS[3] = *reinterpret_cast<const f32x4*>(ap_ + s1g * 8 + 4);             \
    }
#define WRITE_A(RS, BUF)                                                        \
    {                                                                           \
        f16* ad_ = SM + (BUF) * 12288 + tid * 16;                               \
        *reinterpret_cast<f16x8*>(ad_) = __builtin_shufflevector(               \
            __builtin_convertvector(RS[0], f16x4),                              \
            __builtin_convertvector(RS[1], f16x4), 0, 1, 2, 3, 4, 5, 6, 7);     \
        *reinterpret_cast<f16x8*>(ad_ + 8) = __builtin_shufflevector(           \
            __builtin_convertvector(RS[2], f16x4),                              \
            __builtin_convertvector(RS[3], f16x4), 0, 1, 2, 3, 4, 5, 6, 7);     \
    }
#define TILE_BODY(T, RISS, RWR)                                                 \
    {                                                                           \
        const int buf_ = (T) % 3;                                               \
        if ((T) + 2 < NT) {                                                     \
            LOAD_A(RISS, (T) + 2);                                              \
            stageB(((T) + 2) % 3, (T) + 2);                                     \
            asm volatile("" ::: "memory");                                      \
        }                                                                       \
        f16x8 a_[4], b_[8];                                                     \
        _Pragma("unroll") for (int m = 0; m < 4; ++m) a_[m] = LDA(buf_, m);     \
        _Pragma("unroll") for (int n = 0; n < 8; ++n) b_[n] = LDB(buf_, n);     \
        __builtin_amdgcn_s_setprio(1);                                          \
        _Pragma("unroll") for (int m = 0; m < 4; ++m)                           \
            _Pragma("unroll") for (int n = 0; n < 8; ++n)                       \
                acc[m][n] = __builtin_amdgcn_mfma_f32_16x16x32_f16(             \
                    a_[m], b_[n], acc[m][n], 0, 0, 0);                          \
        __builtin_amdgcn_s_setprio(0);                                          \
        if ((T) + 1 < NT) {                                                     \
            if ((T) + 2 < NT) { asm volatile("s_waitcnt vmcnt(8)" ::: "memory"); } \
            else              { asm volatile("s_waitcnt vmcnt(0)" ::: "memory"); } \
            WRITE_A(RWR, ((T) + 1) % 3);                                        \
            asm volatile("s_waitcnt lgkmcnt(0)" ::: "memory");                  \
            __builtin_amdgcn_s_barrier();                                       \
        }                                                                       \
    }

    LOAD_A(rA0, 0);
    stageB(0, 0);
    asm volatile("" ::: "memory");
    LOAD_A(rA1, 1);
    stageB(1, 1);
    asm volatile("s_waitcnt vmcnt(8)" ::: "memory");
    WRITE_A(rA0, 0);
    asm volatile("s_waitcnt lgkmcnt(0)" ::: "memory");
    __builtin_amdgcn_s_barrier();

    int t = 0;
    for (; t < NT - 2; t += 2) {
        TILE_BODY(t,     rA0, rA1);
        TILE_BODY(t + 1, rA1, rA0);
    }
    TILE_BODY(NT - 2, rA0, rA1);
    TILE_BODY(NT - 1, rA1, rA0);
#undef TILE_BODY
#undef WRITE_A
#undef LOAD_A

    const float* bias = (seg == 0) ? b0 : (seg == 1) ? b1 : b2;
#pragma unroll
    for (int n = 0; n < 8; ++n) {
        const int lc = n0 + wc * 128 + n * 16 + lr;
        const float bvv = bias[lc];
#pragma unroll
        for (int m = 0; m < 4; ++m) {
            const int row = m0 + wr * 64 + m * 16 + lg * 4;
            if (seg == 2) { // V transposed: VT[B][H*HD][S]
                const int bb = row >> 11, s0 = row & 2047;
                f16x4 v;
#pragma unroll
                for (int r = 0; r < 4; ++r) v[r] = (f16)(acc[m][n][r] + bvv);
                *reinterpret_cast<f16x4*>(VtB + ((size_t)(bb * D_ + lc)) * S_ + s0) = v;
            } else {
                f16* dst = seg ? Kb : Qb;
#pragma unroll
                for (int r = 0; r < 4; ++r)
                    dst[(size_t)(row + r) * D_ + lc] = (f16)(acc[m][n][r] + bvv);
            }
        }
    }
}

// ---------------------------------------------------------------- output GEMM, triple-buffered (frozen)
__global__ __launch_bounds__(256, 2) void gemm_out3(const f16* __restrict__ A,
                                                    const f16* __restrict__ Wt,
                                                    const float* __restrict__ bias,
                                                    float* __restrict__ Cout) {
    extern __shared__ __align__(16) f16 SM[];
    constexpr int K = D_;
    constexpr int NT = K / 32;
    const int id = (int)blockIdx.x;
    const int work = (id & 7) * 32 + (id >> 3);
    const int wy = work >> 2, wx = work & 3;
    const int m0 = wy * 128, n0 = wx * 256;
    const int tid = (int)threadIdx.x;
    const int w = tid >> 6, lr = tid & 15, lg = (tid & 63) >> 4;
    const int wr = w >> 1, wc = w & 1;
    const int sw = (lr >> 1) & 3;

    auto stage = [&](int buf, int kt) {
        const int kk0 = kt * 32;
        f16* base = SM + buf * 12288;
#pragma unroll
        for (int j = 0; j < 2; ++j) {
            const int c = j * 256 + tid;
            const int row = c >> 2;
            const int ks = ((c & 3) ^ ((row >> 1) & 3)) * 8;
            gload_lds16(A + (size_t)(m0 + row) * K + kk0 + ks,
                        base + (j * 256 + w * 64) * 8);
        }
#pragma unroll
        for (int j = 0; j < 4; ++j) {
            const int c = j * 256 + tid;
            const int row = c >> 2;
            const int ks = ((c & 3) ^ ((row >> 1) & 3)) * 8;
            gload_lds16(Wt + (size_t)(n0 + row) * K + kk0 + ks,
                        base + 4096 + (j * 256 + w * 64) * 8);
        }
    };
    auto LDA = [&](int buf, int m) -> f16x8 {
        return *reinterpret_cast<const f16x8*>(
            SM + buf * 12288 + (wr * 64 + m * 16 + lr) * 32 + ((lg ^ sw) * 8));
    };
    auto LDB = [&](int buf, int n) -> f16x8 {
        return *reinterpret_cast<const f16x8*>(
            SM + buf * 12288 + 4096 + (wc * 128 + n * 16 + lr) * 32 + ((lg ^ sw) * 8));
    };

    f32x4 acc[4][8] = {};
    stage(0, 0);
    stage(1, 1);
    asm volatile("s_waitcnt vmcnt(6)" ::: "memory");
    __builtin_amdgcn_s_barrier();

    int buf = 0;
    for (int t = 0; t < NT; ++t) {
        if (t + 2 < NT) {
            int nb = buf + 2; if (nb >= 3) nb -= 3;
            stage(nb, t + 2);
        }
        f16x8 a[4], b[8];
#pragma unroll
        for (int m = 0; m < 4; ++m) a[m] = LDA(buf, m);
#pragma unroll
        for (int n = 0; n < 8; ++n) b[n] = LDB(buf, n);
        __builtin_amdgcn_s_setprio(1);
#pragma unroll
        for (int m = 0; m < 4; ++m)
#pragma unroll
            for (int n = 0; n < 8; ++n)
                acc[m][n] = __builtin_amdgcn_mfma_f32_16x16x32_f16(a[m], b[n], acc[m][n], 0, 0, 0);
        __builtin_amdgcn_s_setprio(0);
        if (t + 2 < NT) {
            asm volatile("s_waitcnt vmcnt(6)" ::: "memory");
        } else if (t + 1 < NT) {
            asm volatile("s_waitcnt vmcnt(0)" ::: "memory");
        }
        __builtin_amdgcn_s_barrier();
        if (++buf >= 3) buf = 0;
    }
#pragma unroll
    for (int n = 0; n < 8; ++n) {
        const int col = n0 + wc * 128 + n * 16 + lr;
        const float bvv = bias[col];
#pragma unroll
        for (int m = 0; m < 4; ++m) {
            const int row = m0 + wr * 64 + m * 16 + lg * 4;
#pragma unroll
            for (int r = 0; r < 4; ++r)
                Cout[(size_t)(row + r) * D_ + col] = acc[m][n][r] + bvv;
        }
    }
}

// ---------------------------------------------------------------- causal flash attention
// grid (H, B, 16): ONE 128-row q-tile per block, qt = 15 - z (z slowest dispatch
// dim -> heaviest tiles launch first, light ones backfill the tail).
// id%8 = h%8 -> each XCD owns 2 heads x 4 batches: K+V set = 4MB = L2-resident.
// LDS 50KB -> 3 blocks/CU (was capped at 2 by the 512-block paired grid).
// Inner loop identical to r16-verified version.
__global__ __launch_bounds__(256, 3) void attn_kernel(const f16* __restrict__ Q,
                                                      const f16* __restrict__ Kg,
                                                      const f16* __restrict__ Vt,
                                                      f16* __restrict__ Z) {
    __shared__ __align__(16) f16 KL[2][64 * 64];
    __shared__ __align__(16) f16 VL[2][64 * 64];
    __shared__ __align__(16) f16 Pl[4][32][72];
    const int h = blockIdx.x, b = blockIdx.y;
    const int qt = 15 - (int)blockIdx.z; // heavy tiles dispatch first
    const int tid = threadIdx.x, w = tid >> 6, l = tid & 63, lr = l & 15, lg = l >> 4;
    const size_t base   = ((size_t)b * S_) * D_ + h * HD_;
    const size_t vtbase = ((size_t)(b * D_ + h * HD_)) * S_;
    const f16* __restrict__ Kbase = Kg + base;
    const f16* __restrict__ Vbase = Vt + vtbase;
    const float sc = 0.125f * 1.44269504f; // 1/sqrt(64) * log2(e)
    const int sw_xor = lr & 7;
    f16x8 onesv;
#pragma unroll
    for (int i = 0; i < 8; ++i) onesv[i] = (f16)1.0f;

    auto stageKV = [&](int buf, int t0) {
#pragma unroll
        for (int i = 0; i < 2; ++i) {
            const int c = i * 256 + tid;
            const int row = c >> 3, g16 = (c & 7) ^ (row & 7);
            f16* dstK = &KL[buf][(i * 256 + w * 64) * 8];
            f16* dstV = &VL[buf][(i * 256 + w * 64) * 8];
            gload_lds16(Kbase + (size_t)(t0 + row) * D_ + g16 * 8, dstK);
            gload_lds16(Vbase + (size_t)row * S_ + t0 + g16 * 8, dstV);
        }
    };

    const int q0 = qt * 128, wq0 = q0 + w * 32;
    const int ntw = ((wq0 + 31) >> 6) + 1;
    const int ntb = qt * 2 + 2;

    f16x8 qf[2][2];
#pragma unroll
    for (int mf = 0; mf < 2; ++mf)
#pragma unroll
        for (int kd = 0; kd < 2; ++kd)
            qf[mf][kd] = *reinterpret_cast<const f16x8*>(
                Q + base + (size_t)(wq0 + mf * 16 + lr) * D_ + kd * 32 + lg * 8);

    f32x4 zacc[2][4] = {};
    f32x4 lsv[2] = {};
    float mrun[2] = {-3.0e38f, -3.0e38f};

    stageKV(0, 0);
    for (int t = 0; t < ntb; ++t) {
        const int buf = t & 1;
        if (t + 1 < ntb) {
            stageKV(buf ^ 1, (t + 1) * 64);
            asm volatile("s_waitcnt vmcnt(4)" ::: "memory");
        } else {
            asm volatile("s_waitcnt vmcnt(0)" ::: "memory");
        }
        __builtin_amdgcn_s_barrier();
        if (t < ntw) {
            const int t0 = t * 64;
            f16x8 kf[2][4];
#pragma unroll
            for (int kd = 0; kd < 2; ++kd)
#pragma unroll
                for (int n = 0; n < 4; ++n)
                    kf[kd][n] = *reinterpret_cast<const f16x8*>(
                        &KL[buf][(n * 16 + lr) * 64 + (((kd * 4 + lg) ^ sw_xor) * 8)]);
            f32x4 sf[2][4] = {};
            __builtin_amdgcn_s_setprio(1);
#pragma unroll
            for (int kd = 0; kd < 2; ++kd)
#pragma unroll
                for (int n = 0; n < 4; ++n)
#pragma unroll
                    for (int mf = 0; mf < 2; ++mf)
                        sf[mf][n] = __builtin_amdgcn_mfma_f32_16x16x32_f16(kf[kd][n], qf[mf][kd], sf[mf][n], 0, 0, 0);
            __builtin_amdgcn_s_setprio(0);
            f16x8 vf[2][4];
#pragma unroll
            for (int kt = 0; kt < 2; ++kt)
#pragma unroll
                for (int n = 0; n < 4; ++n)
                    vf[kt][n] = *reinterpret_cast<const f16x8*>(
                        &VL[buf][(n * 16 + lr) * 64 + (((kt * 4 + lg) ^ sw_xor) * 8)]);
            if (t == ntw - 1) {
#pragma unroll
                for (int mf = 0; mf < 2; ++mf)
#pragma unroll
                    for (int n = 0; n < 4; ++n)
#pragma unroll
                        for (int r = 0; r < 4; ++r)
                            if ((t0 + n * 16 + lg * 4 + r) > (wq0 + mf * 16 + lr))
                                sf[mf][n][r] = -3.0e38f;
            }
#pragma unroll
            for (int mf = 0; mf < 2; ++mf) {
                f32x4 t4;
#pragma unroll
                for (int r = 0; r < 4; ++r)
                    t4[r] = fmaxf(fmaxf(sf[mf][0][r], sf[mf][1][r]), fmaxf(sf[mf][2][r], sf[mf][3][r]));
                float vmax = fmaxf(fmaxf(t4[0], t4[1]), fmaxf(t4[2], t4[3]));
                vmax = fmaxf(vmax, __shfl_xor(vmax, 16));
                vmax = fmaxf(vmax, __shfl_xor(vmax, 32));
                const float vs = vmax * sc;
                const bool norm = !__all(vs <= mrun[mf] + 10.0f);
                if (norm) {
                    const float mnew = fmaxf(mrun[mf], vs);
                    const float al = __builtin_amdgcn_exp2f(mrun[mf] - mnew);
                    mrun[mf] = mnew;
#pragma unroll
                    for (int r = 0; r < 4; ++r) {
                        const float ar = __shfl(al, lg * 4 + r);
#pragma unroll
                        for (int n = 0; n < 4; ++n) zacc[mf][n][r] *= ar;
                        lsv[mf][r] *= ar;
                    }
                }
#pragma unroll
                for (int n = 0; n < 4; ++n) {
                    f32x4 p;
#pragma unroll
                    for (int r = 0; r < 4; ++r)
                        p[r] = __builtin_amdgcn_exp2f(fmaf(sf[mf][n][r], sc, -mrun[mf]));
                    f16x4 pv;
#pragma unroll
                    for (int r = 0; r < 4; ++r) pv[r] = (f16)p[r];
                    *reinterpret_cast<f16x4*>(&Pl[w][mf * 16 + lr][n * 16 + lg * 4]) = pv;
                }
            }
#pragma unroll
            for (int kt = 0; kt < 2; ++kt) {
                f16x8 pa[2];
#pragma unroll
                for (int mf = 0; mf < 2; ++mf)
                    pa[mf] = *reinterpret_cast<const f16x8*>(&Pl[w][mf * 16 + lr][kt * 32 + lg * 8]);
                __builtin_amdgcn_s_setprio(1);
#pragma unroll
                for (int n = 0; n < 4; ++n)
#pragma unroll
                    for (int mf = 0; mf < 2; ++mf)
                        zacc[mf][n] = __builtin_amdgcn_mfma_f32_16x16x32_f16(pa[mf], vf[kt][n], zacc[mf][n], 0, 0, 0);
#pragma unroll
                for (int mf = 0; mf < 2; ++mf)
                    lsv[mf] = __builtin_amdgcn_mfma_f32_16x16x32_f16(pa[mf], onesv, lsv[mf], 0, 0, 0);
                __builtin_amdgcn_s_setprio(0);
            }
        }
        __builtin_amdgcn_s_barrier();
    }
#pragma unroll
    for (int mf = 0; mf < 2; ++mf) {
        f32x4 inv;
#pragma unroll
        for (int r = 0; r < 4; ++r) inv[r] = 1.0f / lsv[mf][r];
#pragma unroll
        for (int r = 0; r < 4; ++r)
#pragma unroll
            for (int n = 0; n < 4; ++n)
                Z[base + (size_t)(wq0 + mf * 16 + lg * 4 + r) * D_ + n * 16 + lr] =
                    (f16)(zacc[mf][n][r] * inv[r]);
    }
}

// ---------------------------------------------------------------- launcher
extern "C" void kernel_launch(void* const* d_in, const int* in_sizes, int n_in,
                              void* d_out, int out_size, void* d_ws, size_t ws_size,
                              hipStream_t stream) {
    const float* data    = (const float*)d_in[0];
    const float* context = (const float*)d_in[1];
    const float* Wq = (const float*)d_in[2];
    const float* bq = (const float*)d_in[3];
    const float* Wk = (const float*)d_in[4];
    const float* bk = (const float*)d_in[5];
    const float* Wv = (const float*)d_in[6];
    const float* bv = (const float*)d_in[7];
    const float* Wo = (const float*)d_in[8];
    const float* bo = (const float*)d_in[9];

    const size_t MD = (size_t)M_ * D_;
    const size_t DD = (size_t)D_ * D_;
    f16* WqT   = (f16*)d_ws;  // WqT,WkT,WvT,WoT contiguous
    f16* WoT   = WqT + 3 * DD;
    f16* Qb    = WqT + 4 * DD;
    f16* Kb    = Qb + MD;
    f16* VtB   = Kb + MD;     // [B][H][HD][S]
    f16* Zb    = VtB + MD;

    transpose_cvt4_kernel<<<dim3(32, 32, 4), 256, 0, stream>>>(Wq, Wk, Wv, Wo, WqT);

    (void)hipFuncSetAttribute(reinterpret_cast<const void*>(gemm_qkvf),
                              hipFuncAttributeMaxDynamicSharedMemorySize, 73728);
    (void)hipFuncSetAttribute(reinterpret_cast<const void*>(gemm_out3),
                              hipFuncAttributeMaxDynamicSharedMemorySize, 73728);

    gemm_qkvf<<<768, 256, 73728, stream>>>(data, context, WqT, bq, bk, bv,
                                           Qb, Kb, VtB);

    attn_kernel<<<dim3(H_, B_, 16), 256, 0, stream>>>(Qb, Kb, VtB, Zb);

    gemm_out3<<<256, 256, 73728, stream>>>(Zb, WoT, bo, (float*)d_out);
}